// Round 11
// baseline (310.850 us; speedup 1.0000x reference)
//
#include <hip/hip_runtime.h>
#include <hip/hip_bf16.h>
#include <cstdint>
#include <cstddef>

#define N_ATOM 8192
#define N_EDGE 65536
#define DEG    16
#define DIM    64
#define BK     64

typedef __attribute__((ext_vector_type(8))) short bf16x8_t;
typedef __attribute__((ext_vector_type(4))) float f32x4_t;

__device__ __forceinline__ float sigmoidf_(float z) {
  return 1.0f / (1.0f + __expf(-z));
}
__device__ __forceinline__ float lrelu_(float z) {
  return z > 0.0f ? z : 0.01f * z;
}
__device__ __forceinline__ unsigned short f2bfu(float f) {
  union { __hip_bfloat16 h; unsigned short u; } v;
  v.h = __float2bfloat16(f);
  return v.u;
}
__device__ __forceinline__ float bf2f(unsigned short u) {
  union { unsigned int i; float f; } v;
  v.i = ((unsigned int)u) << 16;
  return v.f;
}
__device__ __forceinline__ float4 cvt4f(ushort4 u) {
  return make_float4(bf2f(u.x), bf2f(u.y), bf2f(u.z), bf2f(u.w));
}
__device__ __forceinline__ ushort4 cvt4b(float4 f) {
  ushort4 u;
  u.x = f2bfu(f.x); u.y = f2bfu(f.y); u.z = f2bfu(f.z); u.w = f2bfu(f.w);
  return u;
}
__device__ __forceinline__ bf16x8_t cvt8(const float4 a, const float4 b) {
  bf16x8_t r;
  r[0] = (short)f2bfu(a.x); r[1] = (short)f2bfu(a.y);
  r[2] = (short)f2bfu(a.z); r[3] = (short)f2bfu(a.w);
  r[4] = (short)f2bfu(b.x); r[5] = (short)f2bfu(b.y);
  r[6] = (short)f2bfu(b.z); r[7] = (short)f2bfu(b.w);
  return r;
}
__device__ __forceinline__ void gload16(const void* g, void* l) {
  __builtin_amdgcn_global_load_lds(
      (const __attribute__((address_space(1))) void*)g,
      (__attribute__((address_space(3))) void*)l, 16, 0, 0);
}

// ---------------------------------------------------------------------------
// front: blocks [0,512): x = embed[fp]; hsT_a = bf16(relu(x@W+b))^T
//        blocks [512,1536): 64 bond rows each: bond_bf = bf16(bfeat@bW+bb);
//                           B0 = bf16(bond_row @ Wbn0)
//        blocks [1536,1600): miRNA partials mp2[b][64]
__global__ __launch_bounds__(256) void k_front(
    const int* __restrict__ fp, const float* __restrict__ emb,
    float* __restrict__ x, const float* __restrict__ W,
    const float* __restrict__ b, unsigned short* __restrict__ hsT,
    const float* __restrict__ bfeat, const float* __restrict__ bW,
    const float* __restrict__ bb, unsigned short* __restrict__ bond_bf,
    const float* __restrict__ Wbn0, unsigned short* __restrict__ B_bf,
    const float* __restrict__ words, const float* __restrict__ fcW,
    float* __restrict__ mp2) {
  __shared__ float ps[64][68];
  __shared__ float Ws[64][64];
  const int t = threadIdx.x;
  const int r = t >> 4, dq = t & 15, d0 = dq * 4;
  if (blockIdx.x < (N_ATOM / 16)) {
    const int row = blockIdx.x * 16 + r;
    float4 v = reinterpret_cast<const float4*>(emb)[(size_t)fp[row] * 16 + dq];
    reinterpret_cast<float4*>(x)[(size_t)row * 16 + dq] = v;
    *reinterpret_cast<float4*>(&ps[r][d0]) = v;
#pragma unroll
    for (int q = 0; q < 4; ++q) {
      int p = t + q * 256;
      reinterpret_cast<float4*>(&Ws[0][0])[p] =
          reinterpret_cast<const float4*>(W)[p];
    }
    __syncthreads();
    float4 acc = reinterpret_cast<const float4*>(b)[dq];
#pragma unroll
    for (int k = 0; k < 64; ++k) {
      float xv = ps[r][k];
      float4 wv = *reinterpret_cast<const float4*>(&Ws[k][d0]);
      acc.x = fmaf(xv, wv.x, acc.x);
      acc.y = fmaf(xv, wv.y, acc.y);
      acc.z = fmaf(xv, wv.z, acc.z);
      acc.w = fmaf(xv, wv.w, acc.w);
    }
    float a4[4] = {acc.x, acc.y, acc.z, acc.w};
#pragma unroll
    for (int j = 0; j < 4; ++j)
      hsT[(size_t)(d0 + j) * N_ATOM + row] = f2bfu(fmaxf(a4[j], 0.0f));
  } else if (blockIdx.x < (N_ATOM / 16 + N_EDGE / 64)) {
    const int row0 = (blockIdx.x - N_ATOM / 16) * 64;
    float4 acc[4];
#pragma unroll
    for (int g = 0; g < 4; ++g) acc[g] = reinterpret_cast<const float4*>(bb)[dq];
#pragma unroll
    for (int k = 0; k < 10; ++k) {
      float4 wv = reinterpret_cast<const float4*>(bW)[k * 16 + dq];
#pragma unroll
      for (int g = 0; g < 4; ++g) {
        float xv = bfeat[(size_t)(row0 + g * 16 + r) * 10 + k];
        acc[g].x = fmaf(xv, wv.x, acc[g].x);
        acc[g].y = fmaf(xv, wv.y, acc[g].y);
        acc[g].z = fmaf(xv, wv.z, acc[g].z);
        acc[g].w = fmaf(xv, wv.w, acc[g].w);
      }
    }
#pragma unroll
    for (int g = 0; g < 4; ++g) {
      int row = row0 + g * 16 + r;
      reinterpret_cast<ushort4*>(bond_bf)[(size_t)row * 16 + dq] = cvt4b(acc[g]);
      *reinterpret_cast<float4*>(&ps[g * 16 + r][d0]) = acc[g];
    }
#pragma unroll
    for (int q = 0; q < 4; ++q) {
      int p = t + q * 256;
      reinterpret_cast<float4*>(&Ws[0][0])[p] =
          reinterpret_cast<const float4*>(Wbn0)[p];
    }
    __syncthreads();
    float4 a2[4];
#pragma unroll
    for (int g = 0; g < 4; ++g) a2[g] = make_float4(0.f, 0.f, 0.f, 0.f);
    for (int k = 0; k < 64; ++k) {
      float4 wv = *reinterpret_cast<const float4*>(&Ws[k][d0]);
#pragma unroll
      for (int g = 0; g < 4; ++g) {
        float xv = ps[g * 16 + r][k];
        a2[g].x = fmaf(xv, wv.x, a2[g].x);
        a2[g].y = fmaf(xv, wv.y, a2[g].y);
        a2[g].z = fmaf(xv, wv.z, a2[g].z);
        a2[g].w = fmaf(xv, wv.w, a2[g].w);
      }
    }
#pragma unroll
    for (int g = 0; g < 4; ++g) {
      int row = row0 + g * 16 + r;
      reinterpret_cast<ushort4*>(B_bf)[(size_t)row * 16 + dq] = cvt4b(a2[g]);
    }
  } else {
    const int mb = blockIdx.x - (N_ATOM / 16 + N_EDGE / 64);
    const int k = mb * 16 + r;
    float wv = words[k];
    float4 fv = reinterpret_cast<const float4*>(fcW)[(size_t)k * 16 + dq];
    float4 acc = make_float4(wv * fv.x, wv * fv.y, wv * fv.z, wv * fv.w);
    float4* red4 = reinterpret_cast<float4*>(&Ws[0][0]);
    red4[t] = acc;
    __syncthreads();
    for (int h = 8; h >= 1; h >>= 1) {
      if (r < h) {
        float4 o = red4[t + h * 16];
        acc.x += o.x; acc.y += o.y; acc.z += o.z; acc.w += o.w;
        red4[t] = acc;
      }
      __syncthreads();
    }
    if (r == 0) reinterpret_cast<float4*>(mp2)[mb * 16 + dq] = acc;
  }
}

// ---------------------------------------------------------------------------
// Fused full-K adjacency GEMM (BM=16, 512 blocks, 3-deep prefetch):
//   res[16x64] = adj[row block, :] @ hs      (bf16 MFMA, fp32 acc)
// epilogue:
//   v = x + res; x = v
//   mode 0:  hsOut = bf16(relu(v @ Wn + bn))^T         (pass 1)
//   mode 1:  atom_f = v; A0 = bf16(v @ Wn + bn)        (pass 2)
__global__ __launch_bounds__(256) void k_adjfused(
    const float* __restrict__ adj, const unsigned short* __restrict__ hsIn,
    float* __restrict__ x, float* __restrict__ atom_f,
    const float* __restrict__ Wn, const float* __restrict__ bn,
    unsigned short* __restrict__ hsOut, unsigned short* __restrict__ A0,
    int mode) {
  __shared__ float          Abuf[3][16 * BK];     // 3 x 4 KB
  __shared__ unsigned short Bbuf[3][64 * BK];     // 3 x 8 KB
  const int t = threadIdx.x;
  const int lane = t & 63, w = t >> 6;
  const int lr = lane & 15, lg = lane >> 4;
  const int row0 = blockIdx.x * 16;
  const int NSTEP = N_ATOM / BK;   // 128

  // A staging: 256 16B-chunks, 1/thread. chunk c=t: row=c>>4, u=c&15,
  // u' = (u&8) | ((u&7)^(row&7))  (inverse swizzle on global source)
  const int arow = t >> 4, au = t & 15;
  const int aus = (au & 8) | ((au & 7) ^ (arow & 7));
  const size_t aSrc = (size_t)(row0 + arow) * N_ATOM + aus * 4;
  const int aLds = w * 256;   // float idx, wave-uniform
  // B staging: 512 chunks, 2/thread. chunk c: row=c>>3, u=c&7, u'=u^(row&7)
  size_t bSrc[2]; int bLds[2];
#pragma unroll
  for (int j = 0; j < 2; ++j) {
    int c = j * 256 + t;
    int brow = c >> 3, bu = c & 7;
    int bus = bu ^ (brow & 7);
    bSrc[j] = (size_t)brow * N_ATOM + bus * 8;
    bLds[j] = j * 2048 + w * 512;   // ushort idx, wave-uniform
  }

  f32x4_t acc = (f32x4_t){0.f, 0.f, 0.f, 0.f};

#define STAGE(buf, kt)                                                        \
  {                                                                           \
    gload16(adj + aSrc + (size_t)(kt) * BK, &Abuf[buf][aLds]);                \
    _Pragma("unroll")                                                         \
    for (int j = 0; j < 2; ++j)                                               \
      gload16(hsIn + bSrc[j] + (size_t)(kt) * BK, &Bbuf[buf][bLds[j]]);       \
  }

  STAGE(0, 0);
  STAGE(1, 1);
  int cur = 0;
  for (int kt = 0; kt < NSTEP; ++kt) {
    if (kt + 2 < NSTEP) {
      int nb = cur + 2; if (nb >= 3) nb -= 3;
      STAGE(nb, kt + 2);                          // 3 fresh loads, 2 tiles deep
      asm volatile("s_waitcnt vmcnt(6)" ::: "memory");  // tile-kt landed
    } else if (kt + 1 < NSTEP) {
      asm volatile("s_waitcnt vmcnt(3)" ::: "memory");
    } else {
      asm volatile("s_waitcnt vmcnt(0)" ::: "memory");
    }
    __builtin_amdgcn_s_barrier();
    __builtin_amdgcn_sched_barrier(0);
#pragma unroll
    for (int kf = 0; kf < 2; ++kf) {
      int ua = kf * 8 + ((2 * lg) ^ (lr & 7));
      int ub = kf * 8 + ((2 * lg + 1) ^ (lr & 7));
      float4 fa = *reinterpret_cast<const float4*>(&Abuf[cur][lr * 64 + ua * 4]);
      float4 fb = *reinterpret_cast<const float4*>(&Abuf[cur][lr * 64 + ub * 4]);
      bf16x8_t a = cvt8(fa, fb);
      int Rb = w * 16 + lr;
      int us = (kf * 4 + lg) ^ (Rb & 7);
      bf16x8_t bv = *reinterpret_cast<const bf16x8_t*>(&Bbuf[cur][Rb * 64 + us * 8]);
      acc = __builtin_amdgcn_mfma_f32_16x16x32_bf16(a, bv, acc, 0, 0, 0);
    }
    __builtin_amdgcn_sched_barrier(0);
    __builtin_amdgcn_s_barrier();   // all waves done reading buf `cur`
    cur = cur + 1; if (cur >= 3) cur = 0;
  }
#undef STAGE

  // ---- epilogue: finish rows locally -------------------------------------
  float* xs  = &Abuf[0][0];                         // [16][68] padded, 4.25 KB
  float* Wsh = reinterpret_cast<float*>(&Bbuf[0][0]);   // [64][64] fp32, 16 KB
  // scatter acc into xs: row = lg*4+rg, col = w*16+lr
#pragma unroll
  for (int rg = 0; rg < 4; ++rg)
    xs[(lg * 4 + rg) * 68 + w * 16 + lr] = acc[rg];
  // stage Wn (64x64 fp32) into Wsh
#pragma unroll
  for (int q = 0; q < 4; ++q) {
    int p = t + q * 256;
    reinterpret_cast<float4*>(Wsh)[p] = reinterpret_cast<const float4*>(Wn)[p];
  }
  __syncthreads();
  const int r = t >> 4, dq = t & 15, d0 = dq * 4;
  const int row = row0 + r;
  float4 xv = reinterpret_cast<const float4*>(x)[(size_t)row * 16 + dq];
  float4 v = make_float4(xv.x + xs[r * 68 + d0 + 0],
                         xv.y + xs[r * 68 + d0 + 1],
                         xv.z + xs[r * 68 + d0 + 2],
                         xv.w + xs[r * 68 + d0 + 3]);
  reinterpret_cast<float4*>(x)[(size_t)row * 16 + dq] = v;
  if (mode) reinterpret_cast<float4*>(atom_f)[(size_t)row * 16 + dq] = v;
  // write v back (same cells this thread just read -> no cross-thread hazard)
  xs[r * 68 + d0 + 0] = v.x;
  xs[r * 68 + d0 + 1] = v.y;
  xs[r * 68 + d0 + 2] = v.z;
  xs[r * 68 + d0 + 3] = v.w;
  __syncthreads();
  float4 acc2 = reinterpret_cast<const float4*>(bn)[dq];
#pragma unroll
  for (int k = 0; k < 64; ++k) {
    float xk = xs[r * 68 + k];
    float4 wv = *reinterpret_cast<const float4*>(&Wsh[k * 64 + d0]);
    acc2.x = fmaf(xk, wv.x, acc2.x);
    acc2.y = fmaf(xk, wv.y, acc2.y);
    acc2.z = fmaf(xk, wv.z, acc2.z);
    acc2.w = fmaf(xk, wv.w, acc2.w);
  }
  if (mode == 0) {
    float a4[4] = {acc2.x, acc2.y, acc2.z, acc2.w};
#pragma unroll
    for (int j = 0; j < 4; ++j)
      hsOut[(size_t)(d0 + j) * N_ATOM + row] = f2bfu(fmaxf(a4[j], 0.0f));
  } else {
    reinterpret_cast<ushort4*>(A0)[(size_t)row * 16 + dq] = cvt4b(acc2);
  }
}

// ---------------------------------------------------------------------------
// U: atom_f = sigmoid(atom_f + sum_deg lrelu(A[ai]+B[bi]));
//    has_next: A_next = bf16(atom_f_new @ WanN + nbN)
//    else:     mp[block] = colsum over block rows of (x + atom_f_new)
__global__ __launch_bounds__(256) void k_upd(
    const int* __restrict__ adl, const int* __restrict__ bdl,
    const unsigned short* __restrict__ A, const unsigned short* __restrict__ B,
    float* __restrict__ atom_f, const float* __restrict__ WanN,
    const float* __restrict__ nbN, unsigned short* __restrict__ A_next,
    const float* __restrict__ x, float* __restrict__ mp, int has_next) {
  __shared__ float xs[16][68];
  __shared__ float Ws[64][64];
  int t = threadIdx.x;
  int r = t >> 4, dq = t & 15, d0 = dq * 4;
  int n = blockIdx.x * 16 + r;
  float4 s = make_float4(0.f, 0.f, 0.f, 0.f);
#pragma unroll
  for (int g = 0; g < DEG; ++g) {
    int ai = adl[n * DEG + g];
    int bi = bdl[n * DEG + g];
    float4 va = cvt4f(reinterpret_cast<const ushort4*>(A)[(size_t)ai * 16 + dq]);
    float4 vb = cvt4f(reinterpret_cast<const ushort4*>(B)[(size_t)bi * 16 + dq]);
    s.x += lrelu_(va.x + vb.x);
    s.y += lrelu_(va.y + vb.y);
    s.z += lrelu_(va.z + vb.z);
    s.w += lrelu_(va.w + vb.w);
  }
  float4 af = reinterpret_cast<const float4*>(atom_f)[(size_t)n * 16 + dq];
  af.x = sigmoidf_(af.x + s.x);
  af.y = sigmoidf_(af.y + s.y);
  af.z = sigmoidf_(af.z + s.z);
  af.w = sigmoidf_(af.w + s.w);
  reinterpret_cast<float4*>(atom_f)[(size_t)n * 16 + dq] = af;
  if (has_next) {
    *reinterpret_cast<float4*>(&xs[r][d0]) = af;
#pragma unroll
    for (int q = 0; q < 4; ++q) {
      int p = t + q * 256;
      reinterpret_cast<float4*>(&Ws[0][0])[p] =
          reinterpret_cast<const float4*>(WanN)[p];
    }
    __syncthreads();
    float4 acc = reinterpret_cast<const float4*>(nbN)[dq];
#pragma unroll
    for (int k = 0; k < 64; ++k) {
      float xv = xs[r][k];
      float4 wv = *reinterpret_cast<const float4*>(&Ws[k][d0]);
      acc.x = fmaf(xv, wv.x, acc.x);
      acc.y = fmaf(xv, wv.y, acc.y);
      acc.z = fmaf(xv, wv.z, acc.z);
      acc.w = fmaf(xv, wv.w, acc.w);
    }
    reinterpret_cast<ushort4*>(A_next)[(size_t)n * 16 + dq] = cvt4b(acc);
  } else {
    float4 xv = reinterpret_cast<const float4*>(x)[(size_t)n * 16 + dq];
    float4 c = make_float4(af.x + xv.x, af.y + xv.y, af.z + xv.z, af.w + xv.w);
    float4* red4 = reinterpret_cast<float4*>(&Ws[0][0]);
    red4[t] = c;
    __syncthreads();
    for (int h = 8; h >= 1; h >>= 1) {
      if (r < h) {
        float4 o = red4[t + h * 16];
        c.x += o.x; c.y += o.y; c.z += o.z; c.w += o.w;
        red4[t] = c;
      }
      __syncthreads();
    }
    if (r == 0) reinterpret_cast<float4*>(mp)[blockIdx.x * 16 + dq] = c;
  }
}

// ---------------------------------------------------------------------------
// S (64 rows/block): bf_new = sigmoid(bond_bf + (af[i0]+af[i1]) @ sW + sb);
//    write_bond: bond_bf = bf16(bf_new); B_next = bf16(bf_new @ WbnN)
__global__ __launch_bounds__(256) void k_side(
    const int* __restrict__ ibj, const float* __restrict__ atom_f,
    const float* __restrict__ sW, const float* __restrict__ sb,
    unsigned short* __restrict__ bond_bf, const float* __restrict__ WbnN,
    unsigned short* __restrict__ B_next, int write_bond) {
  __shared__ float ps[64][68];
  __shared__ float Ws[64][64];
  int t = threadIdx.x;
  int r = t >> 4, dq = t & 15, d0 = dq * 4;
  int e0 = blockIdx.x * 64;
#pragma unroll
  for (int q = 0; q < 4; ++q) {
    int p = t + q * 256;
    reinterpret_cast<float4*>(&Ws[0][0])[p] = reinterpret_cast<const float4*>(sW)[p];
  }
#pragma unroll
  for (int g = 0; g < 4; ++g) {
    int e = e0 + g * 16 + r;
    int i0 = ibj[e * 2], i1 = ibj[e * 2 + 1];
    float4 p0 = reinterpret_cast<const float4*>(atom_f)[(size_t)i0 * 16 + dq];
    float4 p1 = reinterpret_cast<const float4*>(atom_f)[(size_t)i1 * 16 + dq];
    *reinterpret_cast<float4*>(&ps[g * 16 + r][d0]) =
        make_float4(p0.x + p1.x, p0.y + p1.y, p0.z + p1.z, p0.w + p1.w);
  }
  __syncthreads();
  float4 acc[4];
#pragma unroll
  for (int g = 0; g < 4; ++g) acc[g] = reinterpret_cast<const float4*>(sb)[dq];
  for (int k = 0; k < 64; ++k) {
    float4 wv = *reinterpret_cast<const float4*>(&Ws[k][d0]);
#pragma unroll
    for (int g = 0; g < 4; ++g) {
      float xv = ps[g * 16 + r][k];
      acc[g].x = fmaf(xv, wv.x, acc[g].x);
      acc[g].y = fmaf(xv, wv.y, acc[g].y);
      acc[g].z = fmaf(xv, wv.z, acc[g].z);
      acc[g].w = fmaf(xv, wv.w, acc[g].w);
    }
  }
  float4 bf[4];
#pragma unroll
  for (int g = 0; g < 4; ++g) {
    int e = e0 + g * 16 + r;
    float4 b0 = cvt4f(reinterpret_cast<const ushort4*>(bond_bf)[(size_t)e * 16 + dq]);
    bf[g].x = sigmoidf_(b0.x + acc[g].x);
    bf[g].y = sigmoidf_(b0.y + acc[g].y);
    bf[g].z = sigmoidf_(b0.z + acc[g].z);
    bf[g].w = sigmoidf_(b0.w + acc[g].w);
    if (write_bond)
      reinterpret_cast<ushort4*>(bond_bf)[(size_t)e * 16 + dq] = cvt4b(bf[g]);
  }
  __syncthreads();
#pragma unroll
  for (int g = 0; g < 4; ++g)
    *reinterpret_cast<float4*>(&ps[g * 16 + r][d0]) = bf[g];
#pragma unroll
  for (int q = 0; q < 4; ++q) {
    int p = t + q * 256;
    reinterpret_cast<float4*>(&Ws[0][0])[p] =
        reinterpret_cast<const float4*>(WbnN)[p];
  }
  __syncthreads();
  float4 a2[4];
#pragma unroll
  for (int g = 0; g < 4; ++g) a2[g] = make_float4(0.f, 0.f, 0.f, 0.f);
  for (int k = 0; k < 64; ++k) {
    float4 wv = *reinterpret_cast<const float4*>(&Ws[k][d0]);
#pragma unroll
    for (int g = 0; g < 4; ++g) {
      float xv = ps[g * 16 + r][k];
      a2[g].x = fmaf(xv, wv.x, a2[g].x);
      a2[g].y = fmaf(xv, wv.y, a2[g].y);
      a2[g].z = fmaf(xv, wv.z, a2[g].z);
      a2[g].w = fmaf(xv, wv.w, a2[g].w);
    }
  }
#pragma unroll
  for (int g = 0; g < 4; ++g) {
    int e = e0 + g * 16 + r;
    reinterpret_cast<ushort4*>(B_next)[(size_t)e * 16 + dq] = cvt4b(a2[g]);
  }
}

// ---------------------------------------------------------------------------
// tail: reduce partials (4-way parallel chunks), out layers -> d_out[2]
__global__ __launch_bounds__(256) void k_tail(
    const float* __restrict__ mp, const float* __restrict__ mp2,
    const float* __restrict__ fcb, const float* __restrict__ oW,
    const float* __restrict__ ob, const float* __restrict__ iW,
    const float* __restrict__ ib, float* __restrict__ out) {
  __shared__ float red[4][64];
  __shared__ float red2[4][64];
  __shared__ float cat[128];
  int t = threadIdx.x;
  int col = t & 63, ch = t >> 6;
  {
    float s = 0.f;
    for (int w = ch * 128; w < ch * 128 + 128; ++w) s += mp[w * 64 + col];
    red[ch][col] = s;
    float s2 = 0.f;
    for (int w = ch * 16; w < ch * 16 + 16; ++w) s2 += mp2[w * 64 + col];
    red2[ch][col] = s2;
  }
  __syncthreads();
  if (t < 64) {
    cat[t] = (red[0][t] + red[1][t] + red[2][t] + red[3][t]) * (1.0f / N_ATOM);
  } else if (t < 128) {
    int d = t - 64;
    cat[64 + d] = fcb[d] + red2[0][d] + red2[1][d] + red2[2][d] + red2[3][d];
  }
  __syncthreads();
  for (int j = 0; j < 2; ++j) {
    float s = 0.f;
    if (t < 128) {
      s = ob[j * 128 + t];
      for (int k = 0; k < 128; ++k)
        s = fmaf(cat[k], oW[(size_t)j * 128 * 128 + k * 128 + t], s);
      s = fmaxf(s, 0.f);
    }
    __syncthreads();
    if (t < 128) cat[t] = s;
    __syncthreads();
  }
  if (t < 2) {
    float s = ib[t];
    for (int k = 0; k < 128; ++k) s = fmaf(cat[k], iW[k * 2 + t], s);
    out[t] = s;
  }
}

// ---------------------------------------------------------------------------
extern "C" void kernel_launch(void* const* d_in, const int* in_sizes, int n_in,
                              void* d_out, int out_size, void* d_ws, size_t ws_size,
                              hipStream_t stream) {
  const int*   fp    = (const int*)  d_in[0];
  const int*   adl   = (const int*)  d_in[1];
  const float* bfeat = (const float*)d_in[2];
  const int*   bdl   = (const int*)  d_in[3];
  const int*   ibj   = (const int*)  d_in[4];
  const float* adj   = (const float*)d_in[5];
  const float* words = (const float*)d_in[6];
  const float* emb   = (const float*)d_in[7];
  const float* bW    = (const float*)d_in[8];
  const float* bb    = (const float*)d_in[9];
  const float* subW  = (const float*)d_in[10];
  const float* subb  = (const float*)d_in[11];
  const float* nW    = (const float*)d_in[12];
  const float* nb    = (const float*)d_in[13];
  const float* sW    = (const float*)d_in[14];
  const float* sb    = (const float*)d_in[15];
  const float* fcW   = (const float*)d_in[16];
  const float* fcb   = (const float*)d_in[17];
  const float* oW    = (const float*)d_in[18];
  const float* ob    = (const float*)d_in[19];
  const float* iW    = (const float*)d_in[20];
  const float* ib    = (const float*)d_in[21];
  float* out = (float*)d_out;

  char* ws = (char*)d_ws;
  const size_t MB = 1ull << 20;
  float*          x      = (float*)(ws + 0 * MB);             // 2 MB
  float*          atom_f = (float*)(ws + 2 * MB);             // 2 MB
  unsigned short* A0_bf  = (unsigned short*)(ws + 4 * MB);    // 1 MB
  unsigned short* A1_bf  = (unsigned short*)(ws + 5 * MB);    // 1 MB
  unsigned short* hsT_a  = (unsigned short*)(ws + 6 * MB);    // 1 MB
  unsigned short* hsT_b  = (unsigned short*)(ws + 7 * MB);    // 1 MB
  unsigned short* bond_bf= (unsigned short*)(ws + 8 * MB);    // 8 MB
  unsigned short* B_bf   = (unsigned short*)(ws + 16 * MB);   // 8 MB
  float*          mp     = (float*)(ws + 24 * MB);            // 128 KB
  float*          mp2    = (float*)(ws + 25 * MB);            // 16 KB

  // front: embed + hs0 + bond(+B0 fused) + miRNA partials
  k_front<<<N_ATOM / 16 + N_EDGE / 64 + 64, 256, 0, stream>>>(
      fp, emb, x, subW, subb, hsT_a, bfeat, bW, bb, bond_bf,
      nW + 64 * 64, B_bf, words, fcW, mp2);
  // pass 1: x += adj@hs0; hsT_b = bf16(relu(x@subW1+subb1))^T
  k_adjfused<<<N_ATOM / 16, 256, 0, stream>>>(
      adj, hsT_a, x, atom_f, subW + 64 * 64, subb + 64, hsT_b, A0_bf, 0);
  // pass 2: x += adj@hs1; atom_f = x; A0 = bf16(x@Wan0+nb0)
  k_adjfused<<<N_ATOM / 16, 256, 0, stream>>>(
      adj, hsT_b, x, atom_f, nW, nb, hsT_a, A0_bf, 1);

  // GNN (A double-buffered; side(2) dead -> skipped)
  // i = 0
  k_upd<<<N_ATOM / 16, 256, 0, stream>>>(adl, bdl, A0_bf, B_bf, atom_f,
                                         nW + 1 * 128 * 64, nb + 1 * 64,
                                         A1_bf, x, mp, 1);
  k_side<<<N_EDGE / 64, 256, 0, stream>>>(ibj, atom_f, sW, sb, bond_bf,
                                          nW + 1 * 128 * 64 + 64 * 64, B_bf, 1);
  // i = 1
  k_upd<<<N_ATOM / 16, 256, 0, stream>>>(adl, bdl, A1_bf, B_bf, atom_f,
                                         nW + 2 * 128 * 64, nb + 2 * 64,
                                         A0_bf, x, mp, 1);
  k_side<<<N_EDGE / 64, 256, 0, stream>>>(ibj, atom_f, sW + 64 * 64, sb + 64,
                                          bond_bf, nW + 2 * 128 * 64 + 64 * 64,
                                          B_bf, 0);
  // i = 2 (atom update only + disease colsum partials)
  k_upd<<<N_ATOM / 16, 256, 0, stream>>>(adl, bdl, A0_bf, B_bf, atom_f,
                                         nullptr, nullptr, nullptr, x, mp, 0);

  // tail
  k_tail<<<1, 256, 0, stream>>>(mp, mp2, fcb, oW, ob, iW, ib, out);
}

// Round 12
// 217.811 us; speedup vs baseline: 1.4272x; 1.4272x over previous
//
#include <hip/hip_runtime.h>
#include <hip/hip_bf16.h>
#include <cstdint>
#include <cstddef>

#define N_ATOM 8192
#define N_EDGE 65536
#define DEG    16
#define DIM    64
#define ADJ_S  4      // split-K slices for adjacency GEMM
#define BM     64
#define BK     64

typedef __attribute__((ext_vector_type(8))) short bf16x8_t;
typedef __attribute__((ext_vector_type(4))) float f32x4_t;

__device__ __forceinline__ float sigmoidf_(float z) {
  return 1.0f / (1.0f + __expf(-z));
}
__device__ __forceinline__ float lrelu_(float z) {
  return z > 0.0f ? z : 0.01f * z;
}
__device__ __forceinline__ unsigned short f2bfu(float f) {
  union { __hip_bfloat16 h; unsigned short u; } v;
  v.h = __float2bfloat16(f);
  return v.u;
}
__device__ __forceinline__ float bf2f(unsigned short u) {
  union { unsigned int i; float f; } v;
  v.i = ((unsigned int)u) << 16;
  return v.f;
}
__device__ __forceinline__ float4 cvt4f(ushort4 u) {
  return make_float4(bf2f(u.x), bf2f(u.y), bf2f(u.z), bf2f(u.w));
}
__device__ __forceinline__ ushort4 cvt4b(float4 f) {
  ushort4 u;
  u.x = f2bfu(f.x); u.y = f2bfu(f.y); u.z = f2bfu(f.z); u.w = f2bfu(f.w);
  return u;
}
__device__ __forceinline__ bf16x8_t cvt8(const float4 a, const float4 b) {
  bf16x8_t r;
  r[0] = (short)f2bfu(a.x); r[1] = (short)f2bfu(a.y);
  r[2] = (short)f2bfu(a.z); r[3] = (short)f2bfu(a.w);
  r[4] = (short)f2bfu(b.x); r[5] = (short)f2bfu(b.y);
  r[6] = (short)f2bfu(b.z); r[7] = (short)f2bfu(b.w);
  return r;
}
__device__ __forceinline__ void gload16(const void* g, void* l) {
  __builtin_amdgcn_global_load_lds(
      (const __attribute__((address_space(1))) void*)g,
      (__attribute__((address_space(3))) void*)l, 16, 0, 0);
}

// ---------------------------------------------------------------------------
// front: blocks [0,512): x = embed[fp]; hsT = bf16(relu(x@W+b))^T
//        blocks [512,1536): 64 bond rows each: bond_bf = bf16(bfeat@bW+bb);
//                           B0 = bf16(bond_row @ Wbn0)   (fused)
//        blocks [1536,1600): miRNA partials mp2[b][64]
__global__ __launch_bounds__(256) void k_front(
    const int* __restrict__ fp, const float* __restrict__ emb,
    float* __restrict__ x, const float* __restrict__ W,
    const float* __restrict__ b, unsigned short* __restrict__ hsT,
    const float* __restrict__ bfeat, const float* __restrict__ bW,
    const float* __restrict__ bb, unsigned short* __restrict__ bond_bf,
    const float* __restrict__ Wbn0, unsigned short* __restrict__ B_bf,
    const float* __restrict__ words, const float* __restrict__ fcW,
    float* __restrict__ mp2) {
  __shared__ float ps[64][68];
  __shared__ float Ws[64][64];
  const int t = threadIdx.x;
  const int r = t >> 4, dq = t & 15, d0 = dq * 4;
  if (blockIdx.x < (N_ATOM / 16)) {
    const int row = blockIdx.x * 16 + r;
    float4 v = reinterpret_cast<const float4*>(emb)[(size_t)fp[row] * 16 + dq];
    reinterpret_cast<float4*>(x)[(size_t)row * 16 + dq] = v;
    *reinterpret_cast<float4*>(&ps[r][d0]) = v;
#pragma unroll
    for (int q = 0; q < 4; ++q) {
      int p = t + q * 256;
      reinterpret_cast<float4*>(&Ws[0][0])[p] =
          reinterpret_cast<const float4*>(W)[p];
    }
    __syncthreads();
    float4 acc = reinterpret_cast<const float4*>(b)[dq];
#pragma unroll
    for (int k = 0; k < 64; ++k) {
      float xv = ps[r][k];
      float4 wv = *reinterpret_cast<const float4*>(&Ws[k][d0]);
      acc.x = fmaf(xv, wv.x, acc.x);
      acc.y = fmaf(xv, wv.y, acc.y);
      acc.z = fmaf(xv, wv.z, acc.z);
      acc.w = fmaf(xv, wv.w, acc.w);
    }
    float a4[4] = {acc.x, acc.y, acc.z, acc.w};
#pragma unroll
    for (int j = 0; j < 4; ++j)
      hsT[(size_t)(d0 + j) * N_ATOM + row] = f2bfu(fmaxf(a4[j], 0.0f));
  } else if (blockIdx.x < (N_ATOM / 16 + N_EDGE / 64)) {
    const int row0 = (blockIdx.x - N_ATOM / 16) * 64;
    float4 acc[4];
#pragma unroll
    for (int g = 0; g < 4; ++g) acc[g] = reinterpret_cast<const float4*>(bb)[dq];
#pragma unroll
    for (int k = 0; k < 10; ++k) {
      float4 wv = reinterpret_cast<const float4*>(bW)[k * 16 + dq];
#pragma unroll
      for (int g = 0; g < 4; ++g) {
        float xv = bfeat[(size_t)(row0 + g * 16 + r) * 10 + k];
        acc[g].x = fmaf(xv, wv.x, acc[g].x);
        acc[g].y = fmaf(xv, wv.y, acc[g].y);
        acc[g].z = fmaf(xv, wv.z, acc[g].z);
        acc[g].w = fmaf(xv, wv.w, acc[g].w);
      }
    }
#pragma unroll
    for (int g = 0; g < 4; ++g) {
      int row = row0 + g * 16 + r;
      reinterpret_cast<ushort4*>(bond_bf)[(size_t)row * 16 + dq] = cvt4b(acc[g]);
      *reinterpret_cast<float4*>(&ps[g * 16 + r][d0]) = acc[g];
    }
#pragma unroll
    for (int q = 0; q < 4; ++q) {
      int p = t + q * 256;
      reinterpret_cast<float4*>(&Ws[0][0])[p] =
          reinterpret_cast<const float4*>(Wbn0)[p];
    }
    __syncthreads();
    float4 a2[4];
#pragma unroll
    for (int g = 0; g < 4; ++g) a2[g] = make_float4(0.f, 0.f, 0.f, 0.f);
    for (int k = 0; k < 64; ++k) {
      float4 wv = *reinterpret_cast<const float4*>(&Ws[k][d0]);
#pragma unroll
      for (int g = 0; g < 4; ++g) {
        float xv = ps[g * 16 + r][k];
        a2[g].x = fmaf(xv, wv.x, a2[g].x);
        a2[g].y = fmaf(xv, wv.y, a2[g].y);
        a2[g].z = fmaf(xv, wv.z, a2[g].z);
        a2[g].w = fmaf(xv, wv.w, a2[g].w);
      }
    }
#pragma unroll
    for (int g = 0; g < 4; ++g) {
      int row = row0 + g * 16 + r;
      reinterpret_cast<ushort4*>(B_bf)[(size_t)row * 16 + dq] = cvt4b(a2[g]);
    }
  } else {
    const int mb = blockIdx.x - (N_ATOM / 16 + N_EDGE / 64);
    const int k = mb * 16 + r;
    float wv = words[k];
    float4 fv = reinterpret_cast<const float4*>(fcW)[(size_t)k * 16 + dq];
    float4 acc = make_float4(wv * fv.x, wv * fv.y, wv * fv.z, wv * fv.w);
    float4* red4 = reinterpret_cast<float4*>(&Ws[0][0]);
    red4[t] = acc;
    __syncthreads();
    for (int h = 8; h >= 1; h >>= 1) {
      if (r < h) {
        float4 o = red4[t + h * 16];
        acc.x += o.x; acc.y += o.y; acc.z += o.z; acc.w += o.w;
        red4[t] = acc;
      }
      __syncthreads();
    }
    if (r == 0) reinterpret_cast<float4*>(mp2)[mb * 16 + dq] = acc;
  }
}

// ---------------------------------------------------------------------------
// x += sum_s part[s]; hsT = bf16(relu(x@W+b))^T
__global__ __launch_bounds__(256) void k_red_hs(
    const float* __restrict__ part, float* __restrict__ x,
    const float* __restrict__ W, const float* __restrict__ b,
    unsigned short* __restrict__ hsT) {
  __shared__ float xs[16][68];
  __shared__ float Ws[64][64];
  const int t = threadIdx.x;
  const int r = t >> 4, dq = t & 15, d0 = dq * 4;
  const int row = blockIdx.x * 16 + r;
  float4 v = reinterpret_cast<const float4*>(x)[(size_t)row * 16 + dq];
#pragma unroll
  for (int s = 0; s < ADJ_S; ++s) {
    float4 p = reinterpret_cast<const float4*>(part)
                   [(size_t)s * (N_ATOM * 16) + (size_t)row * 16 + dq];
    v.x += p.x; v.y += p.y; v.z += p.z; v.w += p.w;
  }
  reinterpret_cast<float4*>(x)[(size_t)row * 16 + dq] = v;
  *reinterpret_cast<float4*>(&xs[r][d0]) = v;
#pragma unroll
  for (int q = 0; q < 4; ++q) {
    int p = t + q * 256;
    reinterpret_cast<float4*>(&Ws[0][0])[p] =
        reinterpret_cast<const float4*>(W)[p];
  }
  __syncthreads();
  float4 acc = reinterpret_cast<const float4*>(b)[dq];
#pragma unroll
  for (int k = 0; k < 64; ++k) {
    float xv = xs[r][k];
    float4 wv = *reinterpret_cast<const float4*>(&Ws[k][d0]);
    acc.x = fmaf(xv, wv.x, acc.x);
    acc.y = fmaf(xv, wv.y, acc.y);
    acc.z = fmaf(xv, wv.z, acc.z);
    acc.w = fmaf(xv, wv.w, acc.w);
  }
  float a4[4] = {acc.x, acc.y, acc.z, acc.w};
#pragma unroll
  for (int j = 0; j < 4; ++j)
    hsT[(size_t)(d0 + j) * N_ATOM + row] = f2bfu(fmaxf(a4[j], 0.0f));
}

// ---------------------------------------------------------------------------
// LDS-staged split-K bf16-MFMA GEMM with counted-vmcnt barriers (T4):
// per K-step: STAGE(next) -> s_waitcnt vmcnt(6) -> s_barrier -> compute
// -> s_barrier.
__global__ __launch_bounds__(256) void k_adjmm(
    const float* __restrict__ adj, const unsigned short* __restrict__ hsT,
    float* __restrict__ part) {
  __shared__ float          Abuf[2][BM * BK];   // 2 x 16 KB
  __shared__ unsigned short Bbuf[2][64 * BK];   // 2 x 8 KB
  const int t = threadIdx.x;
  const int lane = t & 63, w = t >> 6;
  const int lr = lane & 15, lg = lane >> 4;
  const int row0 = blockIdx.x * BM;
  const int kbase = blockIdx.y * (N_ATOM / ADJ_S);
  const int NSTEP = (N_ATOM / ADJ_S) / BK;   // 32

  size_t aSrc[4]; int aLds[4];
#pragma unroll
  for (int j = 0; j < 4; ++j) {
    int c = j * 256 + t;
    int row = c >> 4, u = c & 15;
    int us = (u & 8) | ((u & 7) ^ (row & 7));
    aSrc[j] = (size_t)(row0 + row) * N_ATOM + kbase + us * 4;
    aLds[j] = j * 1024 + w * 256;
  }
  size_t bSrc[2]; int bLds[2];
#pragma unroll
  for (int j = 0; j < 2; ++j) {
    int c = j * 256 + t;
    int row = c >> 3, u = c & 7;
    int us = u ^ (row & 7);
    bSrc[j] = (size_t)row * N_ATOM + kbase + us * 8;
    bLds[j] = j * 2048 + w * 512;
  }

  f32x4_t acc[4];
#pragma unroll
  for (int n = 0; n < 4; ++n) acc[n] = (f32x4_t){0.f, 0.f, 0.f, 0.f};

#define STAGE(buf, kt)                                                        \
  {                                                                           \
    _Pragma("unroll")                                                         \
    for (int j = 0; j < 4; ++j)                                               \
      gload16(adj + aSrc[j] + (kt) * BK, &Abuf[buf][aLds[j]]);                \
    _Pragma("unroll")                                                         \
    for (int j = 0; j < 2; ++j)                                               \
      gload16(hsT + bSrc[j] + (kt) * BK, &Bbuf[buf][bLds[j]]);                \
  }

  STAGE(0, 0);            // prologue: 6 loads of tile 0 in flight
  int cur = 0;
  const int Rl = w * 16 + lr;
  for (int kt = 0; kt < NSTEP; ++kt) {
    if (kt + 1 < NSTEP) {
      STAGE(cur ^ 1, kt + 1);                     // 6 fresh loads (next tile)
      asm volatile("s_waitcnt vmcnt(6)" ::: "memory");  // tile-kt loads done
    } else {
      asm volatile("s_waitcnt vmcnt(0)" ::: "memory");  // last tile: drain
    }
    __builtin_amdgcn_s_barrier();                 // all waves' tile-kt landed
    __builtin_amdgcn_sched_barrier(0);
#pragma unroll
    for (int kf = 0; kf < 2; ++kf) {
      int ua = kf * 8 + ((2 * lg) ^ (Rl & 7));
      int ub = kf * 8 + ((2 * lg + 1) ^ (Rl & 7));
      float4 fa = *reinterpret_cast<const float4*>(&Abuf[cur][Rl * 64 + ua * 4]);
      float4 fb = *reinterpret_cast<const float4*>(&Abuf[cur][Rl * 64 + ub * 4]);
      bf16x8_t a = cvt8(fa, fb);
#pragma unroll
      for (int n = 0; n < 4; ++n) {
        int Rb = n * 16 + lr;
        int us = (kf * 4 + lg) ^ (Rb & 7);
        bf16x8_t bv = *reinterpret_cast<const bf16x8_t*>(&Bbuf[cur][Rb * 64 + us * 8]);
        acc[n] = __builtin_amdgcn_mfma_f32_16x16x32_bf16(a, bv, acc[n], 0, 0, 0);
      }
    }
    __builtin_amdgcn_sched_barrier(0);
    __builtin_amdgcn_s_barrier();   // all waves done reading buf `cur`
    cur ^= 1;
  }
#undef STAGE

  float* pp = part + (size_t)blockIdx.y * (N_ATOM * DIM);
#pragma unroll
  for (int n = 0; n < 4; ++n)
#pragma unroll
    for (int rg = 0; rg < 4; ++rg) {
      int row = row0 + w * 16 + lg * 4 + rg;
      int col = n * 16 + lr;
      pp[(size_t)row * DIM + col] = acc[n][rg];
    }
}

// ---------------------------------------------------------------------------
// A0: x += sum part; atom_f = x; A0 = bf16(x @ Wan0 + nb0)     (512 blocks)
__global__ __launch_bounds__(256) void k_A0(
    float* __restrict__ atom_f, const float* __restrict__ nW0,
    const float* __restrict__ nb0, unsigned short* __restrict__ A,
    const float* __restrict__ part, float* __restrict__ x) {
  __shared__ float xs[16][68];
  __shared__ float Ws[64][64];
  int t = threadIdx.x;
  int r = t >> 4, dq = t & 15, d0 = dq * 4;
  int row = blockIdx.x * 16 + r;
  float4 v = reinterpret_cast<const float4*>(x)[(size_t)row * 16 + dq];
#pragma unroll
  for (int s = 0; s < ADJ_S; ++s) {
    float4 p = reinterpret_cast<const float4*>(part)
                   [(size_t)s * (N_ATOM * 16) + (size_t)row * 16 + dq];
    v.x += p.x; v.y += p.y; v.z += p.z; v.w += p.w;
  }
  reinterpret_cast<float4*>(x)[(size_t)row * 16 + dq] = v;
  reinterpret_cast<float4*>(atom_f)[(size_t)row * 16 + dq] = v;
  *reinterpret_cast<float4*>(&xs[r][d0]) = v;
#pragma unroll
  for (int q = 0; q < 4; ++q) {
    int p = t + q * 256;
    reinterpret_cast<float4*>(&Ws[0][0])[p] = reinterpret_cast<const float4*>(nW0)[p];
  }
  __syncthreads();
  float4 acc = reinterpret_cast<const float4*>(nb0)[dq];
#pragma unroll
  for (int k = 0; k < 64; ++k) {
    float xv = xs[r][k];
    float4 wv = *reinterpret_cast<const float4*>(&Ws[k][d0]);
    acc.x = fmaf(xv, wv.x, acc.x);
    acc.y = fmaf(xv, wv.y, acc.y);
    acc.z = fmaf(xv, wv.z, acc.z);
    acc.w = fmaf(xv, wv.w, acc.w);
  }
  reinterpret_cast<ushort4*>(A)[(size_t)row * 16 + dq] = cvt4b(acc);
}

// ---------------------------------------------------------------------------
// U: atom_f = sigmoid(atom_f + sum_deg lrelu(A[ai]+B[bi]));
//    has_next: A_next = bf16(atom_f_new @ WanN + nbN)
//    else:     mp[block] = colsum over block rows of (x + atom_f_new)
__global__ __launch_bounds__(256) void k_upd(
    const int* __restrict__ adl, const int* __restrict__ bdl,
    const unsigned short* __restrict__ A, const unsigned short* __restrict__ B,
    float* __restrict__ atom_f, const float* __restrict__ WanN,
    const float* __restrict__ nbN, unsigned short* __restrict__ A_next,
    const float* __restrict__ x, float* __restrict__ mp, int has_next) {
  __shared__ float xs[16][68];
  __shared__ float Ws[64][64];
  int t = threadIdx.x;
  int r = t >> 4, dq = t & 15, d0 = dq * 4;
  int n = blockIdx.x * 16 + r;
  float4 s = make_float4(0.f, 0.f, 0.f, 0.f);
#pragma unroll
  for (int g = 0; g < DEG; ++g) {
    int ai = adl[n * DEG + g];
    int bi = bdl[n * DEG + g];
    float4 va = cvt4f(reinterpret_cast<const ushort4*>(A)[(size_t)ai * 16 + dq]);
    float4 vb = cvt4f(reinterpret_cast<const ushort4*>(B)[(size_t)bi * 16 + dq]);
    s.x += lrelu_(va.x + vb.x);
    s.y += lrelu_(va.y + vb.y);
    s.z += lrelu_(va.z + vb.z);
    s.w += lrelu_(va.w + vb.w);
  }
  float4 af = reinterpret_cast<const float4*>(atom_f)[(size_t)n * 16 + dq];
  af.x = sigmoidf_(af.x + s.x);
  af.y = sigmoidf_(af.y + s.y);
  af.z = sigmoidf_(af.z + s.z);
  af.w = sigmoidf_(af.w + s.w);
  reinterpret_cast<float4*>(atom_f)[(size_t)n * 16 + dq] = af;
  if (has_next) {
    *reinterpret_cast<float4*>(&xs[r][d0]) = af;
#pragma unroll
    for (int q = 0; q < 4; ++q) {
      int p = t + q * 256;
      reinterpret_cast<float4*>(&Ws[0][0])[p] =
          reinterpret_cast<const float4*>(WanN)[p];
    }
    __syncthreads();
    float4 acc = reinterpret_cast<const float4*>(nbN)[dq];
#pragma unroll
    for (int k = 0; k < 64; ++k) {
      float xv = xs[r][k];
      float4 wv = *reinterpret_cast<const float4*>(&Ws[k][d0]);
      acc.x = fmaf(xv, wv.x, acc.x);
      acc.y = fmaf(xv, wv.y, acc.y);
      acc.z = fmaf(xv, wv.z, acc.z);
      acc.w = fmaf(xv, wv.w, acc.w);
    }
    reinterpret_cast<ushort4*>(A_next)[(size_t)n * 16 + dq] = cvt4b(acc);
  } else {
    float4 xv = reinterpret_cast<const float4*>(x)[(size_t)n * 16 + dq];
    float4 c = make_float4(af.x + xv.x, af.y + xv.y, af.z + xv.z, af.w + xv.w);
    float4* red4 = reinterpret_cast<float4*>(&Ws[0][0]);
    red4[t] = c;
    __syncthreads();
    for (int h = 8; h >= 1; h >>= 1) {
      if (r < h) {
        float4 o = red4[t + h * 16];
        c.x += o.x; c.y += o.y; c.z += o.z; c.w += o.w;
        red4[t] = c;
      }
      __syncthreads();
    }
    if (r == 0) reinterpret_cast<float4*>(mp)[blockIdx.x * 16 + dq] = c;
  }
}

// ---------------------------------------------------------------------------
// S (64 rows/block): bf_new = sigmoid(bond_bf + (af[i0]+af[i1]) @ sW + sb);
//    write_bond: bond_bf = bf16(bf_new); B_next = bf16(bf_new @ WbnN)
__global__ __launch_bounds__(256) void k_side(
    const int* __restrict__ ibj, const float* __restrict__ atom_f,
    const float* __restrict__ sW, const float* __restrict__ sb,
    unsigned short* __restrict__ bond_bf, const float* __restrict__ WbnN,
    unsigned short* __restrict__ B_next, int write_bond) {
  __shared__ float ps[64][68];
  __shared__ float Ws[64][64];
  int t = threadIdx.x;
  int r = t >> 4, dq = t & 15, d0 = dq * 4;
  int e0 = blockIdx.x * 64;
#pragma unroll
  for (int q = 0; q < 4; ++q) {
    int p = t + q * 256;
    reinterpret_cast<float4*>(&Ws[0][0])[p] = reinterpret_cast<const float4*>(sW)[p];
  }
#pragma unroll
  for (int g = 0; g < 4; ++g) {
    int e = e0 + g * 16 + r;
    int i0 = ibj[e * 2], i1 = ibj[e * 2 + 1];
    float4 p0 = reinterpret_cast<const float4*>(atom_f)[(size_t)i0 * 16 + dq];
    float4 p1 = reinterpret_cast<const float4*>(atom_f)[(size_t)i1 * 16 + dq];
    *reinterpret_cast<float4*>(&ps[g * 16 + r][d0]) =
        make_float4(p0.x + p1.x, p0.y + p1.y, p0.z + p1.z, p0.w + p1.w);
  }
  __syncthreads();
  float4 acc[4];
#pragma unroll
  for (int g = 0; g < 4; ++g) acc[g] = reinterpret_cast<const float4*>(sb)[dq];
  for (int k = 0; k < 64; ++k) {
    float4 wv = *reinterpret_cast<const float4*>(&Ws[k][d0]);
#pragma unroll
    for (int g = 0; g < 4; ++g) {
      float xv = ps[g * 16 + r][k];
      acc[g].x = fmaf(xv, wv.x, acc[g].x);
      acc[g].y = fmaf(xv, wv.y, acc[g].y);
      acc[g].z = fmaf(xv, wv.z, acc[g].z);
      acc[g].w = fmaf(xv, wv.w, acc[g].w);
    }
  }
  float4 bf[4];
#pragma unroll
  for (int g = 0; g < 4; ++g) {
    int e = e0 + g * 16 + r;
    float4 b0 = cvt4f(reinterpret_cast<const ushort4*>(bond_bf)[(size_t)e * 16 + dq]);
    bf[g].x = sigmoidf_(b0.x + acc[g].x);
    bf[g].y = sigmoidf_(b0.y + acc[g].y);
    bf[g].z = sigmoidf_(b0.z + acc[g].z);
    bf[g].w = sigmoidf_(b0.w + acc[g].w);
    if (write_bond)
      reinterpret_cast<ushort4*>(bond_bf)[(size_t)e * 16 + dq] = cvt4b(bf[g]);
  }
  __syncthreads();   // everyone done reading ps/Ws of GEMM1
#pragma unroll
  for (int g = 0; g < 4; ++g)
    *reinterpret_cast<float4*>(&ps[g * 16 + r][d0]) = bf[g];
#pragma unroll
  for (int q = 0; q < 4; ++q) {
    int p = t + q * 256;
    reinterpret_cast<float4*>(&Ws[0][0])[p] =
        reinterpret_cast<const float4*>(WbnN)[p];
  }
  __syncthreads();
  float4 a2[4];
#pragma unroll
  for (int g = 0; g < 4; ++g) a2[g] = make_float4(0.f, 0.f, 0.f, 0.f);
  for (int k = 0; k < 64; ++k) {
    float4 wv = *reinterpret_cast<const float4*>(&Ws[k][d0]);
#pragma unroll
    for (int g = 0; g < 4; ++g) {
      float xv = ps[g * 16 + r][k];
      a2[g].x = fmaf(xv, wv.x, a2[g].x);
      a2[g].y = fmaf(xv, wv.y, a2[g].y);
      a2[g].z = fmaf(xv, wv.z, a2[g].z);
      a2[g].w = fmaf(xv, wv.w, a2[g].w);
    }
  }
#pragma unroll
  for (int g = 0; g < 4; ++g) {
    int e = e0 + g * 16 + r;
    reinterpret_cast<ushort4*>(B_next)[(size_t)e * 16 + dq] = cvt4b(a2[g]);
  }
}

// ---------------------------------------------------------------------------
// tail: reduce partials (4-way parallel chunks), out layers -> d_out[2]
__global__ __launch_bounds__(256) void k_tail(
    const float* __restrict__ mp, const float* __restrict__ mp2,
    const float* __restrict__ fcb, const float* __restrict__ oW,
    const float* __restrict__ ob, const float* __restrict__ iW,
    const float* __restrict__ ib, float* __restrict__ out) {
  __shared__ float red[4][64];
  __shared__ float red2[4][64];
  __shared__ float cat[128];
  int t = threadIdx.x;
  int col = t & 63, ch = t >> 6;
  {
    float s = 0.f;
    for (int w = ch * 128; w < ch * 128 + 128; ++w) s += mp[w * 64 + col];
    red[ch][col] = s;
    float s2 = 0.f;
    for (int w = ch * 16; w < ch * 16 + 16; ++w) s2 += mp2[w * 64 + col];
    red2[ch][col] = s2;
  }
  __syncthreads();
  if (t < 64) {
    cat[t] = (red[0][t] + red[1][t] + red[2][t] + red[3][t]) * (1.0f / N_ATOM);
  } else if (t < 128) {
    int d = t - 64;
    cat[64 + d] = fcb[d] + red2[0][d] + red2[1][d] + red2[2][d] + red2[3][d];
  }
  __syncthreads();
  for (int j = 0; j < 2; ++j) {
    float s = 0.f;
    if (t < 128) {
      s = ob[j * 128 + t];
      for (int k = 0; k < 128; ++k)
        s = fmaf(cat[k], oW[(size_t)j * 128 * 128 + k * 128 + t], s);
      s = fmaxf(s, 0.f);
    }
    __syncthreads();
    if (t < 128) cat[t] = s;
    __syncthreads();
  }
  if (t < 2) {
    float s = ib[t];
    for (int k = 0; k < 128; ++k) s = fmaf(cat[k], iW[k * 2 + t], s);
    out[t] = s;
  }
}

// ---------------------------------------------------------------------------
extern "C" void kernel_launch(void* const* d_in, const int* in_sizes, int n_in,
                              void* d_out, int out_size, void* d_ws, size_t ws_size,
                              hipStream_t stream) {
  const int*   fp    = (const int*)  d_in[0];
  const int*   adl   = (const int*)  d_in[1];
  const float* bfeat = (const float*)d_in[2];
  const int*   bdl   = (const int*)  d_in[3];
  const int*   ibj   = (const int*)  d_in[4];
  const float* adj   = (const float*)d_in[5];
  const float* words = (const float*)d_in[6];
  const float* emb   = (const float*)d_in[7];
  const float* bW    = (const float*)d_in[8];
  const float* bb    = (const float*)d_in[9];
  const float* subW  = (const float*)d_in[10];
  const float* subb  = (const float*)d_in[11];
  const float* nW    = (const float*)d_in[12];
  const float* nb    = (const float*)d_in[13];
  const float* sW    = (const float*)d_in[14];
  const float* sb    = (const float*)d_in[15];
  const float* fcW   = (const float*)d_in[16];
  const float* fcb   = (const float*)d_in[17];
  const float* oW    = (const float*)d_in[18];
  const float* ob    = (const float*)d_in[19];
  const float* iW    = (const float*)d_in[20];
  const float* ib    = (const float*)d_in[21];
  float* out = (float*)d_out;

  char* ws = (char*)d_ws;
  const size_t MB = 1ull << 20;
  float*          x      = (float*)(ws + 0 * MB);             // 2 MB
  float*          atom_f = (float*)(ws + 2 * MB);             // 2 MB
  unsigned short* A0_bf  = (unsigned short*)(ws + 4 * MB);    // 1 MB
  unsigned short* A1_bf  = (unsigned short*)(ws + 5 * MB);    // 1 MB
  unsigned short* hsT    = (unsigned short*)(ws + 6 * MB);    // 1 MB
  float*          mp     = (float*)(ws + 7 * MB);             // 128 KB
  float*          mp2    = (float*)(ws + 7 * MB + 512 * 1024);// 16 KB
  unsigned short* bond_bf= (unsigned short*)(ws + 8 * MB);    // 8 MB
  unsigned short* B_bf   = (unsigned short*)(ws + 16 * MB);   // 8 MB
  float*          part   = (float*)(ws + 32 * MB);            // 8 MB (4 slices)

  dim3 gmm(N_ATOM / BM, ADJ_S);

  // front: embed + hs0 + bond(+B0 fused, 64 rows/blk) + miRNA partials
  k_front<<<N_ATOM / 16 + N_EDGE / 64 + 64, 256, 0, stream>>>(
      fp, emb, x, subW, subb, hsT, bfeat, bW, bb, bond_bf,
      nW + 64 * 64, B_bf, words, fcW, mp2);
  // sub_graph radius 0
  k_adjmm<<<gmm, 256, 0, stream>>>(adj, hsT, part);
  k_red_hs<<<N_ATOM / 16, 256, 0, stream>>>(part, x, subW + 64 * 64,
                                            subb + 64, hsT);
  // sub_graph radius 1 (reduction folded into A0)
  k_adjmm<<<gmm, 256, 0, stream>>>(adj, hsT, part);

  // GNN (A double-buffered; side(2) dead -> skipped)
  k_A0<<<N_ATOM / 16, 256, 0, stream>>>(atom_f, nW, nb, A0_bf, part, x);
  // i = 0
  k_upd<<<N_ATOM / 16, 256, 0, stream>>>(adl, bdl, A0_bf, B_bf, atom_f,
                                         nW + 1 * 128 * 64, nb + 1 * 64,
                                         A1_bf, x, mp, 1);
  k_side<<<N_EDGE / 64, 256, 0, stream>>>(ibj, atom_f, sW, sb, bond_bf,
                                          nW + 1 * 128 * 64 + 64 * 64, B_bf, 1);
  // i = 1
  k_upd<<<N_ATOM / 16, 256, 0, stream>>>(adl, bdl, A1_bf, B_bf, atom_f,
                                         nW + 2 * 128 * 64, nb + 2 * 64,
                                         A0_bf, x, mp, 1);
  k_side<<<N_EDGE / 64, 256, 0, stream>>>(ibj, atom_f, sW + 64 * 64, sb + 64,
                                          bond_bf, nW + 2 * 128 * 64 + 64 * 64,
                                          B_bf, 0);
  // i = 2 (atom update only + disease colsum partials)
  k_upd<<<N_ATOM / 16, 256, 0, stream>>>(adl, bdl, A0_bf, B_bf, atom_f,
                                         nullptr, nullptr, nullptr, x, mp, 0);

  // tail
  k_tail<<<1, 256, 0, stream>>>(mp, mp2, fcb, oW, ob, iW, ib, out);
}